// Round 17
// baseline (248.298 us; speedup 1.0000x reference)
//
#include <hip/hip_runtime.h>

typedef _Float16 half_t;
typedef _Float16 half2_t __attribute__((ext_vector_type(2)));
typedef float f4 __attribute__((ext_vector_type(4)));

#define BB 4
#define NN 1024
#define NH 8
#define KD 16
#define ID 128
#define NT 4      // rows per block
#define LGR 520   // f16 per (r,p) half-row (512 + 8 pad)

static constexpr size_t OUT_SZ   = (size_t)BB * NN * 128;
static constexpr size_t ATT_SZ   = (size_t)NH * BB * NN * NN;
static constexpr size_t OFF_OSS  = OUT_SZ;
static constexpr size_t OFF_ST   = OUT_SZ + ATT_SZ;
static constexpr size_t HSTRIDE  = (size_t)BB * NN * NN;

__device__ __forceinline__ float fdot2u(unsigned int a, unsigned int b, float c) {
    union { unsigned int u; half2_t h; } ua, ub;
    ua.u = a; ub.u = b;
    return __builtin_amdgcn_fdot2(ua.h, ub.h, c, false);
}

// ---------------- Kernel 1: QKV projection (unchanged) ----------------
__global__ __launch_bounds__(128) void qkv_kernel(
    const float* __restrict__ q,  const float* __restrict__ Wq,
    const float* __restrict__ Wk, const float* __restrict__ Wv,
    half_t* __restrict__ Qh, half_t* __restrict__ Kp, half_t* __restrict__ Vp)
{
    const int bn = blockIdx.x;
    const int j  = threadIdx.x;
    const int h  = j >> 4, k = j & 15;
    const int b  = bn >> 10, n = bn & 1023;

    __shared__ float qrow[ID];
    qrow[j] = q[(size_t)bn * ID + j];
    __syncthreads();

    const float* wq = Wq + h * ID * KD + k;
    const float* wk = Wk + h * ID * KD + k;
    const float* wv = Wv + h * ID * KD + k;
    float aq = 0.f, ak = 0.f, av = 0.f;
#pragma unroll
    for (int i = 0; i < ID; ++i) {
        float x = qrow[i];
        aq = fmaf(x, wq[i * KD], aq);
        ak = fmaf(x, wk[i * KD], ak);
        av = fmaf(x, wv[i * KD], av);
    }
    Qh[(size_t)bn * 128 + j] = (half_t)aq;
    const size_t pr = ((size_t)((b * NH + h) * 8 + (k >> 1)) * NN + n) * 2 + (k & 1);
    Kp[pr] = (half_t)ak;
    Vp[pr] = (half_t)av;
}

// ---------------- Kernel 1b: coalesced transpose Vp -> Vt (unchanged) ----------------
__global__ __launch_bounds__(256) void vtrans_kernel(
    const unsigned int* __restrict__ Vp, half_t* __restrict__ Vt)
{
    const int bh  = blockIdx.x >> 2;
    const int nt  = blockIdx.x & 3;
    const int tid = threadIdx.x;
    const int n0  = nt * 256;

    __shared__ half_t t[16][264];

#pragma unroll
    for (int vp = 0; vp < 8; ++vp) {
        union { unsigned int u; half_t h2[2]; } c;
        c.u = Vp[((size_t)(bh * 8 + vp)) * NN + n0 + tid];
        t[2 * vp + 0][tid] = c.h2[0];
        t[2 * vp + 1][tid] = c.h2[1];
    }
    __syncthreads();
#pragma unroll
    for (int rep = 0; rep < 2; ++rep) {
        const int cch = tid + rep * 256;
        const int row = cch >> 5, col = (cch & 31) * 8;
        const uint4 vv = *reinterpret_cast<const uint4*>(&t[row][col]);
        *reinterpret_cast<uint4*>(Vt + ((size_t)(bh * 16 + row)) * NN + n0 + col) = vv;
    }
}

// ---------------- Kernel 2: R15 structure + K/st/oss register prefetch ----------------
__global__ __launch_bounds__(512, 6) void fused_kernel(
    const float* __restrict__ oss, const float* __restrict__ st,
    const half_t* __restrict__ Qh, const unsigned int* __restrict__ Kp,
    const half_t* __restrict__ Vt,
    const float* __restrict__ w1,  const float* __restrict__ b1,
    const float* __restrict__ w2,  const float* __restrict__ b2,
    const float* __restrict__ Wout, float* __restrict__ out)
{
    const int n0  = blockIdx.x * NT;
    const int b   = blockIdx.y;
    const int tid = threadIdx.x;
    const int rg  = tid >> 7;            // row 0..3
    const int t7  = tid & 127;
    const int mi0 = t7 * 4;              // m-offset within half

    __shared__ __align__(16) unsigned int kst[8 * 512];   // 16 KB K stage
    __shared__ __align__(16) half_t lg[NT * NH * LGR];    // 33.3 KB exp'd probs (one half)
    __shared__ unsigned int qsh[NT][64];
    __shared__ float wsumPart[8][NH];
    __shared__ float headsSh[NT][128];

    if (tid < 256) qsh[tid >> 6][tid & 63] =
        reinterpret_cast<const unsigned int*>(Qh + ((size_t)(b * NN + n0 + (tid >> 6))) * 128)[tid & 63];
    if (tid < 64) wsumPart[tid >> 3][tid & 7] = 0.f;
    __syncthreads();

    // PV role (fixed)
    const int ph   = tid >> 6;
    const int pv   = (tid >> 2) & 15;
    const int psub = tid & 3;

    float pvAcc[NT] = {0.f, 0.f, 0.f, 0.f};

    const int kp = tid >> 6, kc = (tid & 63) * 8;   // K staging role

#pragma unroll 1
    for (int hf = 0; hf < 2; ++hf) {
        float y[4][8];
#pragma unroll
        for (int mo = 0; mo < 4; ++mo)
#pragma unroll
            for (int o = 0; o < 8; ++o) y[mo][o] = b1[o];

        // ---- prologue prefetch for h = 0 ----
        const unsigned int* kSrc0 =
            Kp + ((size_t)((b * NH + 0) * 8 + kp)) * NN + hf * 512 + kc;
        uint4 kA = *reinterpret_cast<const uint4*>(kSrc0);
        uint4 kB = *reinterpret_cast<const uint4*>(kSrc0 + 4);
        const size_t rowOff = ((size_t)(b * NN + n0 + rg)) * NN + hf * 512 + mi0;
        f4 sv_c = __builtin_nontemporal_load(reinterpret_cast<const f4*>(st + rowOff));
        f4 ov_c = __builtin_nontemporal_load(reinterpret_cast<const f4*>(oss + rowOff));

#pragma unroll 1
        for (int h = 0; h < NH; ++h) {
            __syncthreads();   // prior kst readers done (drains prefetch loads too)
            *reinterpret_cast<uint4*>(&kst[kp * 512 + kc])     = kA;
            *reinterpret_cast<uint4*>(&kst[kp * 512 + kc + 4]) = kB;
            __syncthreads();   // kst ready

            const size_t idx = (size_t)h * HSTRIDE + rowOff;

            // ---- prefetch next h (registers; consumed next iteration) ----
            if (h < 7) {
                const unsigned int* kSrcN =
                    Kp + ((size_t)((b * NH + h + 1) * 8 + kp)) * NN + hf * 512 + kc;
                kA = *reinterpret_cast<const uint4*>(kSrcN);
                kB = *reinterpret_cast<const uint4*>(kSrcN + 4);
            }
            const f4 sv = sv_c, ov = ov_c;
            if (h < 7) {
                const size_t idxN = idx + HSTRIDE;
                sv_c = __builtin_nontemporal_load(reinterpret_cast<const f4*>(st + idxN));
                ov_c = __builtin_nontemporal_load(reinterpret_cast<const f4*>(oss + idxN));
            }

            // passthrough stores (data already in regs)
            *reinterpret_cast<f4*>(out + OFF_ST + idx)  = sv;
            *reinterpret_cast<f4*>(out + OFF_OSS + idx) = ov;
            const float svv[4] = {sv.x, sv.y, sv.z, sv.w};
            const float ovv[4] = {ov.x, ov.y, ov.z, ov.w};

            float acc[4] = {0.f, 0.f, 0.f, 0.f};
#pragma unroll
            for (int kp2 = 0; kp2 < 8; ++kp2) {
                const uint4 k4 = *reinterpret_cast<const uint4*>(&kst[kp2 * 512 + mi0]);
                const unsigned int qp = qsh[rg][h * 8 + kp2];
                acc[0] = fdot2u(k4.x, qp, acc[0]);
                acc[1] = fdot2u(k4.y, qp, acc[1]);
                acc[2] = fdot2u(k4.z, qp, acc[2]);
                acc[3] = fdot2u(k4.w, qp, acc[3]);
            }

            float w1c[8], w1o[8];
#pragma unroll
            for (int o = 0; o < 8; ++o) { w1c[o] = w1[o * 16 + h]; w1o[o] = w1[o * 16 + 8 + h]; }
#pragma unroll
            for (int mo = 0; mo < 4; ++mo) {
                const float c = (acc[mo] + svv[mo]) * 0.25f;
#pragma unroll
                for (int o = 0; o < 8; ++o)
                    y[mo][o] = fmaf(c, w1c[o], fmaf(ovv[mo], w1o[o], y[mo][o]));
            }
        }

        // ---- layer 2 -> exp -> lg (this half) + prob-sum reduce ----
        float lgv[8][4];
#pragma unroll
        for (int mo = 0; mo < 4; ++mo) {
            float z[8];
#pragma unroll
            for (int o = 0; o < 8; ++o) z[o] = fmaxf(y[mo][o], 0.f);
#pragma unroll
            for (int p = 0; p < 8; ++p) {
                float a = b2[p];
#pragma unroll
                for (int o = 0; o < 8; ++o) a = fmaf(z[o], w2[p * 8 + o], a);
                lgv[p][mo] = a;
            }
        }
        float psum[8];
#pragma unroll
        for (int p = 0; p < 8; ++p) {
            const float e0 = __expf(lgv[p][0]);
            const float e1 = __expf(lgv[p][1]);
            const float e2 = __expf(lgv[p][2]);
            const float e3 = __expf(lgv[p][3]);
            psum[p] = (e0 + e1) + (e2 + e3);
            union { uint2 u; half_t h4[4]; } w;
            w.h4[0] = (half_t)e0; w.h4[1] = (half_t)e1;
            w.h4[2] = (half_t)e2; w.h4[3] = (half_t)e3;
            *reinterpret_cast<uint2*>(&lg[(rg * NH + p) * LGR + mi0]) = w.u;
        }
#pragma unroll
        for (int p = 0; p < 8; ++p)
#pragma unroll
            for (int s = 32; s > 0; s >>= 1)
                psum[p] += __shfl_xor(psum[p], s);
        if ((tid & 63) == 0) {
            const int w = tid >> 6;
#pragma unroll
            for (int p = 0; p < 8; ++p) wsumPart[w][p] += psum[p];
        }
        __syncthreads();   // lg + wsum ready

        // ---- PV accumulate for this half ----
        {
            const unsigned int* vr = reinterpret_cast<const unsigned int*>(
                Vt + ((size_t)((b * NH + ph) * KD + pv)) * NN + hf * 512);
#pragma unroll 2
            for (int c2 = 0; c2 < 16; ++c2) {
                const int mo = (c2 * 4 + psub) * 8;
                const uint4 vv = *reinterpret_cast<const uint4*>(vr + mo / 2);
#pragma unroll
                for (int r = 0; r < NT; ++r) {
                    const uint4 ww = *reinterpret_cast<const uint4*>(&lg[(r * NH + ph) * LGR + mo]);
                    pvAcc[r] = fdot2u(vv.x, ww.x, pvAcc[r]);
                    pvAcc[r] = fdot2u(vv.y, ww.y, pvAcc[r]);
                    pvAcc[r] = fdot2u(vv.z, ww.z, pvAcc[r]);
                    pvAcc[r] = fdot2u(vv.w, ww.w, pvAcc[r]);
                }
            }
        }
        __syncthreads();   // lg consumable next half
    }

    // ---- normalize -> headsSh ----
#pragma unroll
    for (int r = 0; r < NT; ++r) {
        pvAcc[r] += __shfl_xor(pvAcc[r], 1);
        pvAcc[r] += __shfl_xor(pvAcc[r], 2);
    }
    if (psub == 0) {
#pragma unroll
        for (int r = 0; r < NT; ++r) {
            const float s = wsumPart[2 * r][ph] + wsumPart[2 * r + 1][ph];
            headsSh[r][ph * 16 + pv] = pvAcc[r] * (1.0f / s);
        }
    }
    __syncthreads();

    // ---- output projection: 4 rows share Wout loads ----
    {
        const int e  = tid & 127;
        const int q2 = tid >> 7;
        float a[NT] = {0.f, 0.f, 0.f, 0.f};
#pragma unroll
        for (int ii = 0; ii < 32; ++ii) {
            const int i = q2 * 32 + ii;
            const float wr = Wout[(size_t)i * 128 + e];
#pragma unroll
            for (int r = 0; r < NT; ++r) a[r] = fmaf(headsSh[r][i], wr, a[r]);
        }
        float* red = reinterpret_cast<float*>(kst);
#pragma unroll
        for (int r = 0; r < NT; ++r) red[(q2 * NT + r) * 128 + e] = a[r];
        __syncthreads();
        {
            const int r = tid >> 7, e2 = tid & 127;
            out[((size_t)(b * NN + n0 + r)) * 128 + e2] =
                red[(0 * NT + r) * 128 + e2] + red[(1 * NT + r) * 128 + e2] +
                red[(2 * NT + r) * 128 + e2] + red[(3 * NT + r) * 128 + e2];
        }
    }
}

extern "C" void kernel_launch(void* const* d_in, const int* in_sizes, int n_in,
                              void* d_out, int out_size, void* d_ws, size_t ws_size,
                              hipStream_t stream) {
    const float* q    = (const float*)d_in[0];
    const float* oss  = (const float*)d_in[1];
    const float* st   = (const float*)d_in[2];
    const float* Wq   = (const float*)d_in[3];
    const float* Wk   = (const float*)d_in[4];
    const float* Wv   = (const float*)d_in[5];
    const float* w1   = (const float*)d_in[6];
    const float* b1   = (const float*)d_in[7];
    const float* w2   = (const float*)d_in[8];
    const float* b2   = (const float*)d_in[9];
    const float* Wout = (const float*)d_in[10];
    float* out = (float*)d_out;

    half_t* Qh = (half_t*)d_ws;
    half_t* Kp = (half_t*)((char*)d_ws + 1u * 1024u * 1024u);
    half_t* Vp = (half_t*)((char*)d_ws + 2u * 1024u * 1024u);
    half_t* Vt = (half_t*)((char*)d_ws + 3u * 1024u * 1024u);

    qkv_kernel<<<dim3(BB * NN), dim3(128), 0, stream>>>(q, Wq, Wk, Wv, Qh, Kp, Vp);
    vtrans_kernel<<<dim3(32 * 4), dim3(256), 0, stream>>>((const unsigned int*)Vp, Vt);
    fused_kernel<<<dim3(NN / NT, BB), dim3(512), 0, stream>>>(
        oss, st, Qh, (const unsigned int*)Kp, Vt,
        w1, b1, w2, b2, Wout, out);
}

// Round 18
// 153.901 us; speedup vs baseline: 1.6134x; 1.6134x over previous
//
#include <hip/hip_runtime.h>

typedef _Float16 half_t;
typedef _Float16 half2_t __attribute__((ext_vector_type(2)));
typedef float f4 __attribute__((ext_vector_type(4)));

#define BB 4
#define NN 1024
#define NH 8
#define KD 16
#define ID 128
#define NT 4      // rows per block
#define LGR 520   // f16 per (r,p) half-row (512 + 8 pad)

static constexpr size_t OUT_SZ   = (size_t)BB * NN * 128;
static constexpr size_t ATT_SZ   = (size_t)NH * BB * NN * NN;
static constexpr size_t OFF_OSS  = OUT_SZ;
static constexpr size_t OFF_ST   = OUT_SZ + ATT_SZ;
static constexpr size_t HSTRIDE  = (size_t)BB * NN * NN;

__device__ __forceinline__ float fdot2u(unsigned int a, unsigned int b, float c) {
    union { unsigned int u; half2_t h; } ua, ub;
    ua.u = a; ub.u = b;
    return __builtin_amdgcn_fdot2(ua.h, ub.h, c, false);
}

// ---------------- Kernel 1: QKV projection ----------------
__global__ __launch_bounds__(128) void qkv_kernel(
    const float* __restrict__ q,  const float* __restrict__ Wq,
    const float* __restrict__ Wk, const float* __restrict__ Wv,
    half_t* __restrict__ Qh, half_t* __restrict__ Kp, half_t* __restrict__ Vp)
{
    const int bn = blockIdx.x;
    const int j  = threadIdx.x;
    const int h  = j >> 4, k = j & 15;
    const int b  = bn >> 10, n = bn & 1023;

    __shared__ float qrow[ID];
    qrow[j] = q[(size_t)bn * ID + j];
    __syncthreads();

    const float* wq = Wq + h * ID * KD + k;
    const float* wk = Wk + h * ID * KD + k;
    const float* wv = Wv + h * ID * KD + k;
    float aq = 0.f, ak = 0.f, av = 0.f;
#pragma unroll
    for (int i = 0; i < ID; ++i) {
        float x = qrow[i];
        aq = fmaf(x, wq[i * KD], aq);
        ak = fmaf(x, wk[i * KD], ak);
        av = fmaf(x, wv[i * KD], av);
    }
    Qh[(size_t)bn * 128 + j] = (half_t)aq;
    const size_t pr = ((size_t)((b * NH + h) * 8 + (k >> 1)) * NN + n) * 2 + (k & 1);
    Kp[pr] = (half_t)ak;
    Vp[pr] = (half_t)av;
}

// ---------------- Kernel 1b: coalesced transpose Vp -> Vt ----------------
__global__ __launch_bounds__(256) void vtrans_kernel(
    const unsigned int* __restrict__ Vp, half_t* __restrict__ Vt)
{
    const int bh  = blockIdx.x >> 2;
    const int nt  = blockIdx.x & 3;
    const int tid = threadIdx.x;
    const int n0  = nt * 256;

    __shared__ half_t t[16][264];

#pragma unroll
    for (int vp = 0; vp < 8; ++vp) {
        union { unsigned int u; half_t h2[2]; } c;
        c.u = Vp[((size_t)(bh * 8 + vp)) * NN + n0 + tid];
        t[2 * vp + 0][tid] = c.h2[0];
        t[2 * vp + 1][tid] = c.h2[1];
    }
    __syncthreads();
#pragma unroll
    for (int rep = 0; rep < 2; ++rep) {
        const int cch = tid + rep * 256;
        const int row = cch >> 5, col = (cch & 31) * 8;
        const uint4 vv = *reinterpret_cast<const uint4*>(&t[row][col]);
        *reinterpret_cast<uint4*>(Vt + ((size_t)(bh * 16 + row)) * NN + n0 + col) = vv;
    }
}

// ---------------- Kernel 2: 4-row fused, K in LDS, two m-halves (R15, measured best) ----------------
__global__ __launch_bounds__(512, 4) void fused_kernel(
    const float* __restrict__ oss, const float* __restrict__ st,
    const half_t* __restrict__ Qh, const unsigned int* __restrict__ Kp,
    const half_t* __restrict__ Vt,
    const float* __restrict__ w1,  const float* __restrict__ b1,
    const float* __restrict__ w2,  const float* __restrict__ b2,
    const float* __restrict__ Wout, float* __restrict__ out)
{
    const int n0  = blockIdx.x * NT;
    const int b   = blockIdx.y;
    const int tid = threadIdx.x;
    const int rg  = tid >> 7;            // row 0..3 (wave-pure: waves 2rg, 2rg+1)
    const int t7  = tid & 127;
    const int mi0 = t7 * 4;              // m-offset within half

    __shared__ __align__(16) unsigned int kst[8 * 512];   // 16 KB K stage; aliased as red later
    __shared__ __align__(16) half_t lg[NT * NH * LGR];    // 33.3 KB exp'd probs (one half)
    __shared__ unsigned int qsh[NT][64];
    __shared__ float wsumPart[8][NH];                      // per-wave prob sums (accum over halves)
    __shared__ float headsSh[NT][128];

    if (tid < 256) qsh[tid >> 6][tid & 63] =
        reinterpret_cast<const unsigned int*>(Qh + ((size_t)(b * NN + n0 + (tid >> 6))) * 128)[tid & 63];
    if (tid < 64) wsumPart[tid >> 3][tid & 7] = 0.f;
    __syncthreads();

    // PV role (fixed): (head, v, sub)
    const int ph   = tid >> 6;
    const int pv   = (tid >> 2) & 15;
    const int psub = tid & 3;

    float pvAcc[NT] = {0.f, 0.f, 0.f, 0.f};

#pragma unroll 1
    for (int hf = 0; hf < 2; ++hf) {
        // ---- pass A for this half: thread owns (row rg, m = hf*512 + mi0 .. +3) ----
        float y[4][8];
#pragma unroll
        for (int mo = 0; mo < 4; ++mo)
#pragma unroll
            for (int o = 0; o < 8; ++o) y[mo][o] = b1[o];

#pragma unroll 1
        for (int h = 0; h < NH; ++h) {
            __syncthreads();   // prior kst readers done
            {
                const int kp = tid >> 6, c = (tid & 63) * 8;
                const unsigned int* src =
                    Kp + ((size_t)((b * NH + h) * 8 + kp)) * NN + hf * 512 + c;
                const uint4 A  = *reinterpret_cast<const uint4*>(src);
                const uint4 B2 = *reinterpret_cast<const uint4*>(src + 4);
                *reinterpret_cast<uint4*>(&kst[kp * 512 + c])     = A;
                *reinterpret_cast<uint4*>(&kst[kp * 512 + c + 4]) = B2;
            }
            __syncthreads();   // kst ready

            const size_t idx = (size_t)h * HSTRIDE +
                ((size_t)(b * NN + n0 + rg)) * NN + hf * 512 + mi0;
            const f4 sv = __builtin_nontemporal_load(reinterpret_cast<const f4*>(st + idx));
            const f4 ov = __builtin_nontemporal_load(reinterpret_cast<const f4*>(oss + idx));
            *reinterpret_cast<f4*>(out + OFF_ST + idx)  = sv;   // passthrough
            *reinterpret_cast<f4*>(out + OFF_OSS + idx) = ov;
            const float svv[4] = {sv.x, sv.y, sv.z, sv.w};
            const float ovv[4] = {ov.x, ov.y, ov.z, ov.w};

            float acc[4] = {0.f, 0.f, 0.f, 0.f};
#pragma unroll
            for (int kp = 0; kp < 8; ++kp) {
                const uint4 k4 = *reinterpret_cast<const uint4*>(&kst[kp * 512 + mi0]);
                const unsigned int qp = qsh[rg][h * 8 + kp];
                acc[0] = fdot2u(k4.x, qp, acc[0]);
                acc[1] = fdot2u(k4.y, qp, acc[1]);
                acc[2] = fdot2u(k4.z, qp, acc[2]);
                acc[3] = fdot2u(k4.w, qp, acc[3]);
            }

            float w1c[8], w1o[8];
#pragma unroll
            for (int o = 0; o < 8; ++o) { w1c[o] = w1[o * 16 + h]; w1o[o] = w1[o * 16 + 8 + h]; }
#pragma unroll
            for (int mo = 0; mo < 4; ++mo) {
                const float c = (acc[mo] + svv[mo]) * 0.25f;
#pragma unroll
                for (int o = 0; o < 8; ++o)
                    y[mo][o] = fmaf(c, w1c[o], fmaf(ovv[mo], w1o[o], y[mo][o]));
            }
        }

        // ---- layer 2 -> exp -> lg (this half) + prob-sum reduce ----
        float lgv[8][4];
#pragma unroll
        for (int mo = 0; mo < 4; ++mo) {
            float z[8];
#pragma unroll
            for (int o = 0; o < 8; ++o) z[o] = fmaxf(y[mo][o], 0.f);
#pragma unroll
            for (int p = 0; p < 8; ++p) {
                float a = b2[p];
#pragma unroll
                for (int o = 0; o < 8; ++o) a = fmaf(z[o], w2[p * 8 + o], a);
                lgv[p][mo] = a;
            }
        }
        float psum[8];
#pragma unroll
        for (int p = 0; p < 8; ++p) {
            const float e0 = __expf(lgv[p][0]);
            const float e1 = __expf(lgv[p][1]);
            const float e2 = __expf(lgv[p][2]);
            const float e3 = __expf(lgv[p][3]);
            psum[p] = (e0 + e1) + (e2 + e3);
            union { uint2 u; half_t h4[4]; } w;
            w.h4[0] = (half_t)e0; w.h4[1] = (half_t)e1;
            w.h4[2] = (half_t)e2; w.h4[3] = (half_t)e3;
            *reinterpret_cast<uint2*>(&lg[(rg * NH + p) * LGR + mi0]) = w.u;
        }
#pragma unroll
        for (int p = 0; p < 8; ++p)
#pragma unroll
            for (int s = 32; s > 0; s >>= 1)
                psum[p] += __shfl_xor(psum[p], s);
        if ((tid & 63) == 0) {
            const int w = tid >> 6;
#pragma unroll
            for (int p = 0; p < 8; ++p) wsumPart[w][p] += psum[p];
        }
        __syncthreads();   // lg + wsum ready

        // ---- PV accumulate for this half ----
        {
            const unsigned int* vr = reinterpret_cast<const unsigned int*>(
                Vt + ((size_t)((b * NH + ph) * KD + pv)) * NN + hf * 512);
#pragma unroll 2
            for (int c2 = 0; c2 < 16; ++c2) {
                const int mo = (c2 * 4 + psub) * 8;     // 8 f16 per chunk
                const uint4 vv = *reinterpret_cast<const uint4*>(vr + mo / 2);
#pragma unroll
                for (int r = 0; r < NT; ++r) {
                    const uint4 ww = *reinterpret_cast<const uint4*>(&lg[(r * NH + ph) * LGR + mo]);
                    pvAcc[r] = fdot2u(vv.x, ww.x, pvAcc[r]);
                    pvAcc[r] = fdot2u(vv.y, ww.y, pvAcc[r]);
                    pvAcc[r] = fdot2u(vv.z, ww.z, pvAcc[r]);
                    pvAcc[r] = fdot2u(vv.w, ww.w, pvAcc[r]);
                }
            }
        }
        __syncthreads();   // lg consumable for overwrite next half
    }

    // ---- normalize -> headsSh ----
#pragma unroll
    for (int r = 0; r < NT; ++r) {
        pvAcc[r] += __shfl_xor(pvAcc[r], 1);
        pvAcc[r] += __shfl_xor(pvAcc[r], 2);
    }
    if (psub == 0) {
#pragma unroll
        for (int r = 0; r < NT; ++r) {
            const float s = wsumPart[2 * r][ph] + wsumPart[2 * r + 1][ph];
            headsSh[r][ph * 16 + pv] = pvAcc[r] * (1.0f / s);
        }
    }
    __syncthreads();

    // ---- output projection: 4 rows share Wout loads ----
    {
        const int e  = tid & 127;
        const int q2 = tid >> 7;             // i-slice 0..3
        float a[NT] = {0.f, 0.f, 0.f, 0.f};
#pragma unroll
        for (int ii = 0; ii < 32; ++ii) {
            const int i = q2 * 32 + ii;
            const float wr = Wout[(size_t)i * 128 + e];
#pragma unroll
            for (int r = 0; r < NT; ++r) a[r] = fmaf(headsSh[r][i], wr, a[r]);
        }
        float* red = reinterpret_cast<float*>(kst);   // 16 slices x 128 = 8 KB (kst dead)
#pragma unroll
        for (int r = 0; r < NT; ++r) red[(q2 * NT + r) * 128 + e] = a[r];
        __syncthreads();
        {
            const int r = tid >> 7, e2 = tid & 127;
            out[((size_t)(b * NN + n0 + r)) * 128 + e2] =
                red[(0 * NT + r) * 128 + e2] + red[(1 * NT + r) * 128 + e2] +
                red[(2 * NT + r) * 128 + e2] + red[(3 * NT + r) * 128 + e2];
        }
    }
}

extern "C" void kernel_launch(void* const* d_in, const int* in_sizes, int n_in,
                              void* d_out, int out_size, void* d_ws, size_t ws_size,
                              hipStream_t stream) {
    const float* q    = (const float*)d_in[0];
    const float* oss  = (const float*)d_in[1];
    const float* st   = (const float*)d_in[2];
    const float* Wq   = (const float*)d_in[3];
    const float* Wk   = (const float*)d_in[4];
    const float* Wv   = (const float*)d_in[5];
    const float* w1   = (const float*)d_in[6];
    const float* b1   = (const float*)d_in[7];
    const float* w2   = (const float*)d_in[8];
    const float* b2   = (const float*)d_in[9];
    const float* Wout = (const float*)d_in[10];
    float* out = (float*)d_out;

    half_t* Qh = (half_t*)d_ws;
    half_t* Kp = (half_t*)((char*)d_ws + 1u * 1024u * 1024u);
    half_t* Vp = (half_t*)((char*)d_ws + 2u * 1024u * 1024u);
    half_t* Vt = (half_t*)((char*)d_ws + 3u * 1024u * 1024u);

    qkv_kernel<<<dim3(BB * NN), dim3(128), 0, stream>>>(q, Wq, Wk, Wv, Qh, Kp, Vp);
    vtrans_kernel<<<dim3(32 * 4), dim3(256), 0, stream>>>((const unsigned int*)Vp, Vt);
    fused_kernel<<<dim3(NN / NT, BB), dim3(512), 0, stream>>>(
        oss, st, Qh, (const unsigned int*)Kp, Vt,
        w1, b1, w2, b2, Wout, out);
}

// Round 19
// 145.830 us; speedup vs baseline: 1.7026x; 1.0553x over previous
//
#include <hip/hip_runtime.h>

typedef _Float16 half_t;
typedef _Float16 half2_t __attribute__((ext_vector_type(2)));
typedef float f4 __attribute__((ext_vector_type(4)));

#define BB 4
#define NN 1024
#define NH 8
#define KD 16
#define ID 128
#define NT 4      // rows per block
#define LGR 520   // f16 per (r,p) half-row (512 + 8 pad)

static constexpr size_t OUT_SZ   = (size_t)BB * NN * 128;
static constexpr size_t ATT_SZ   = (size_t)NH * BB * NN * NN;
static constexpr size_t OFF_OSS  = OUT_SZ;
static constexpr size_t OFF_ST   = OUT_SZ + ATT_SZ;
static constexpr size_t HSTRIDE  = (size_t)BB * NN * NN;

__device__ __forceinline__ float fdot2u(unsigned int a, unsigned int b, float c) {
    union { unsigned int u; half2_t h; } ua, ub;
    ua.u = a; ub.u = b;
    return __builtin_amdgcn_fdot2(ua.h, ub.h, c, false);
}

// Barrier that waits only on LDS ops (lgkmcnt), leaving global loads/stores
// in flight across it. All inter-thread deps in the hot loop are LDS-only,
// so this is semantically sufficient; it removes the vmcnt(0) drain that
// __syncthreads() would emit (the convoy on passthrough-store retire).
__device__ __forceinline__ void lds_barrier() {
    asm volatile("s_waitcnt lgkmcnt(0)\n\ts_barrier" ::: "memory");
}

// ---------------- Kernel 1: QKV projection ----------------
__global__ __launch_bounds__(128) void qkv_kernel(
    const float* __restrict__ q,  const float* __restrict__ Wq,
    const float* __restrict__ Wk, const float* __restrict__ Wv,
    half_t* __restrict__ Qh, half_t* __restrict__ Kp, half_t* __restrict__ Vp)
{
    const int bn = blockIdx.x;
    const int j  = threadIdx.x;
    const int h  = j >> 4, k = j & 15;
    const int b  = bn >> 10, n = bn & 1023;

    __shared__ float qrow[ID];
    qrow[j] = q[(size_t)bn * ID + j];
    __syncthreads();

    const float* wq = Wq + h * ID * KD + k;
    const float* wk = Wk + h * ID * KD + k;
    const float* wv = Wv + h * ID * KD + k;
    float aq = 0.f, ak = 0.f, av = 0.f;
#pragma unroll
    for (int i = 0; i < ID; ++i) {
        float x = qrow[i];
        aq = fmaf(x, wq[i * KD], aq);
        ak = fmaf(x, wk[i * KD], ak);
        av = fmaf(x, wv[i * KD], av);
    }
    Qh[(size_t)bn * 128 + j] = (half_t)aq;
    const size_t pr = ((size_t)((b * NH + h) * 8 + (k >> 1)) * NN + n) * 2 + (k & 1);
    Kp[pr] = (half_t)ak;
    Vp[pr] = (half_t)av;
}

// ---------------- Kernel 1b: coalesced transpose Vp -> Vt ----------------
__global__ __launch_bounds__(256) void vtrans_kernel(
    const unsigned int* __restrict__ Vp, half_t* __restrict__ Vt)
{
    const int bh  = blockIdx.x >> 2;
    const int nt  = blockIdx.x & 3;
    const int tid = threadIdx.x;
    const int n0  = nt * 256;

    __shared__ half_t t[16][264];

#pragma unroll
    for (int vp = 0; vp < 8; ++vp) {
        union { unsigned int u; half_t h2[2]; } c;
        c.u = Vp[((size_t)(bh * 8 + vp)) * NN + n0 + tid];
        t[2 * vp + 0][tid] = c.h2[0];
        t[2 * vp + 1][tid] = c.h2[1];
    }
    __syncthreads();
#pragma unroll
    for (int rep = 0; rep < 2; ++rep) {
        const int cch = tid + rep * 256;
        const int row = cch >> 5, col = (cch & 31) * 8;
        const uint4 vv = *reinterpret_cast<const uint4*>(&t[row][col]);
        *reinterpret_cast<uint4*>(Vt + ((size_t)(bh * 16 + row)) * NN + n0 + col) = vv;
    }
}

// ---------------- Kernel 2: R15 structure + lgkm-only hot-loop barriers ----------------
__global__ __launch_bounds__(512, 4) void fused_kernel(
    const float* __restrict__ oss, const float* __restrict__ st,
    const half_t* __restrict__ Qh, const unsigned int* __restrict__ Kp,
    const half_t* __restrict__ Vt,
    const float* __restrict__ w1,  const float* __restrict__ b1,
    const float* __restrict__ w2,  const float* __restrict__ b2,
    const float* __restrict__ Wout, float* __restrict__ out)
{
    const int n0  = blockIdx.x * NT;
    const int b   = blockIdx.y;
    const int tid = threadIdx.x;
    const int rg  = tid >> 7;            // row 0..3 (wave-pure: waves 2rg, 2rg+1)
    const int t7  = tid & 127;
    const int mi0 = t7 * 4;              // m-offset within half

    __shared__ __align__(16) unsigned int kst[8 * 512];   // 16 KB K stage; aliased as red later
    __shared__ __align__(16) half_t lg[NT * NH * LGR];    // 33.3 KB exp'd probs (one half)
    __shared__ unsigned int qsh[NT][64];
    __shared__ float wsumPart[8][NH];                      // per-wave prob sums (accum over halves)
    __shared__ float headsSh[NT][128];

    if (tid < 256) qsh[tid >> 6][tid & 63] =
        reinterpret_cast<const unsigned int*>(Qh + ((size_t)(b * NN + n0 + (tid >> 6))) * 128)[tid & 63];
    if (tid < 64) wsumPart[tid >> 3][tid & 7] = 0.f;
    __syncthreads();

    // PV role (fixed): (head, v, sub)
    const int ph   = tid >> 6;
    const int pv   = (tid >> 2) & 15;
    const int psub = tid & 3;

    float pvAcc[NT] = {0.f, 0.f, 0.f, 0.f};

#pragma unroll 1
    for (int hf = 0; hf < 2; ++hf) {
        // ---- pass A for this half: thread owns (row rg, m = hf*512 + mi0 .. +3) ----
        float y[4][8];
#pragma unroll
        for (int mo = 0; mo < 4; ++mo)
#pragma unroll
            for (int o = 0; o < 8; ++o) y[mo][o] = b1[o];

#pragma unroll 1
        for (int h = 0; h < NH; ++h) {
            lds_barrier();   // prior kst readers done (LDS-only dep)
            {
                const int kp = tid >> 6, c = (tid & 63) * 8;
                const unsigned int* src =
                    Kp + ((size_t)((b * NH + h) * 8 + kp)) * NN + hf * 512 + c;
                const uint4 A  = *reinterpret_cast<const uint4*>(src);
                const uint4 B2 = *reinterpret_cast<const uint4*>(src + 4);
                *reinterpret_cast<uint4*>(&kst[kp * 512 + c])     = A;
                *reinterpret_cast<uint4*>(&kst[kp * 512 + c + 4]) = B2;
            }
            lds_barrier();   // kst ready (ds_writes retired via lgkmcnt)

            const size_t idx = (size_t)h * HSTRIDE +
                ((size_t)(b * NN + n0 + rg)) * NN + hf * 512 + mi0;
            const f4 sv = __builtin_nontemporal_load(reinterpret_cast<const f4*>(st + idx));
            const f4 ov = __builtin_nontemporal_load(reinterpret_cast<const f4*>(oss + idx));
            *reinterpret_cast<f4*>(out + OFF_ST + idx)  = sv;   // passthrough
            *reinterpret_cast<f4*>(out + OFF_OSS + idx) = ov;
            const float svv[4] = {sv.x, sv.y, sv.z, sv.w};
            const float ovv[4] = {ov.x, ov.y, ov.z, ov.w};

            float acc[4] = {0.f, 0.f, 0.f, 0.f};
#pragma unroll
            for (int kp = 0; kp < 8; ++kp) {
                const uint4 k4 = *reinterpret_cast<const uint4*>(&kst[kp * 512 + mi0]);
                const unsigned int qp = qsh[rg][h * 8 + kp];
                acc[0] = fdot2u(k4.x, qp, acc[0]);
                acc[1] = fdot2u(k4.y, qp, acc[1]);
                acc[2] = fdot2u(k4.z, qp, acc[2]);
                acc[3] = fdot2u(k4.w, qp, acc[3]);
            }

            float w1c[8], w1o[8];
#pragma unroll
            for (int o = 0; o < 8; ++o) { w1c[o] = w1[o * 16 + h]; w1o[o] = w1[o * 16 + 8 + h]; }
#pragma unroll
            for (int mo = 0; mo < 4; ++mo) {
                const float c = (acc[mo] + svv[mo]) * 0.25f;
#pragma unroll
                for (int o = 0; o < 8; ++o)
                    y[mo][o] = fmaf(c, w1c[o], fmaf(ovv[mo], w1o[o], y[mo][o]));
            }
        }

        // ---- layer 2 -> exp -> lg (this half) + prob-sum reduce ----
        float lgv[8][4];
#pragma unroll
        for (int mo = 0; mo < 4; ++mo) {
            float z[8];
#pragma unroll
            for (int o = 0; o < 8; ++o) z[o] = fmaxf(y[mo][o], 0.f);
#pragma unroll
            for (int p = 0; p < 8; ++p) {
                float a = b2[p];
#pragma unroll
                for (int o = 0; o < 8; ++o) a = fmaf(z[o], w2[p * 8 + o], a);
                lgv[p][mo] = a;
            }
        }
        float psum[8];
#pragma unroll
        for (int p = 0; p < 8; ++p) {
            const float e0 = __expf(lgv[p][0]);
            const float e1 = __expf(lgv[p][1]);
            const float e2 = __expf(lgv[p][2]);
            const float e3 = __expf(lgv[p][3]);
            psum[p] = (e0 + e1) + (e2 + e3);
            union { uint2 u; half_t h4[4]; } w;
            w.h4[0] = (half_t)e0; w.h4[1] = (half_t)e1;
            w.h4[2] = (half_t)e2; w.h4[3] = (half_t)e3;
            *reinterpret_cast<uint2*>(&lg[(rg * NH + p) * LGR + mi0]) = w.u;
        }
#pragma unroll
        for (int p = 0; p < 8; ++p)
#pragma unroll
            for (int s = 32; s > 0; s >>= 1)
                psum[p] += __shfl_xor(psum[p], s);
        if ((tid & 63) == 0) {
            const int w = tid >> 6;
#pragma unroll
            for (int p = 0; p < 8; ++p) wsumPart[w][p] += psum[p];
        }
        lds_barrier();   // lg + wsum ready (LDS-only dep)

        // ---- PV accumulate for this half ----
        {
            const unsigned int* vr = reinterpret_cast<const unsigned int*>(
                Vt + ((size_t)((b * NH + ph) * KD + pv)) * NN + hf * 512);
#pragma unroll 2
            for (int c2 = 0; c2 < 16; ++c2) {
                const int mo = (c2 * 4 + psub) * 8;     // 8 f16 per chunk
                const uint4 vv = *reinterpret_cast<const uint4*>(vr + mo / 2);
#pragma unroll
                for (int r = 0; r < NT; ++r) {
                    const uint4 ww = *reinterpret_cast<const uint4*>(&lg[(r * NH + ph) * LGR + mo]);
                    pvAcc[r] = fdot2u(vv.x, ww.x, pvAcc[r]);
                    pvAcc[r] = fdot2u(vv.y, ww.y, pvAcc[r]);
                    pvAcc[r] = fdot2u(vv.z, ww.z, pvAcc[r]);
                    pvAcc[r] = fdot2u(vv.w, ww.w, pvAcc[r]);
                }
            }
        }
        lds_barrier();   // lg consumable for overwrite next half
    }

    // ---- normalize -> headsSh ----
#pragma unroll
    for (int r = 0; r < NT; ++r) {
        pvAcc[r] += __shfl_xor(pvAcc[r], 1);
        pvAcc[r] += __shfl_xor(pvAcc[r], 2);
    }
    if (psub == 0) {
#pragma unroll
        for (int r = 0; r < NT; ++r) {
            const float s = wsumPart[2 * r][ph] + wsumPart[2 * r + 1][ph];
            headsSh[r][ph * 16 + pv] = pvAcc[r] * (1.0f / s);
        }
    }
    __syncthreads();

    // ---- output projection: 4 rows share Wout loads ----
    {
        const int e  = tid & 127;
        const int q2 = tid >> 7;             // i-slice 0..3
        float a[NT] = {0.f, 0.f, 0.f, 0.f};
#pragma unroll
        for (int ii = 0; ii < 32; ++ii) {
            const int i = q2 * 32 + ii;
            const float wr = Wout[(size_t)i * 128 + e];
#pragma unroll
            for (int r = 0; r < NT; ++r) a[r] = fmaf(headsSh[r][i], wr, a[r]);
        }
        float* red = reinterpret_cast<float*>(kst);   // 16 slices x 128 = 8 KB (kst dead)
#pragma unroll
        for (int r = 0; r < NT; ++r) red[(q2 * NT + r) * 128 + e] = a[r];
        __syncthreads();
        {
            const int r = tid >> 7, e2 = tid & 127;
            out[((size_t)(b * NN + n0 + r)) * 128 + e2] =
                red[(0 * NT + r) * 128 + e2] + red[(1 * NT + r) * 128 + e2] +
                red[(2 * NT + r) * 128 + e2] + red[(3 * NT + r) * 128 + e2];
        }
    }
}

extern "C" void kernel_launch(void* const* d_in, const int* in_sizes, int n_in,
                              void* d_out, int out_size, void* d_ws, size_t ws_size,
                              hipStream_t stream) {
    const float* q    = (const float*)d_in[0];
    const float* oss  = (const float*)d_in[1];
    const float* st   = (const float*)d_in[2];
    const float* Wq   = (const float*)d_in[3];
    const float* Wk   = (const float*)d_in[4];
    const float* Wv   = (const float*)d_in[5];
    const float* w1   = (const float*)d_in[6];
    const float* b1   = (const float*)d_in[7];
    const float* w2   = (const float*)d_in[8];
    const float* b2   = (const float*)d_in[9];
    const float* Wout = (const float*)d_in[10];
    float* out = (float*)d_out;

    half_t* Qh = (half_t*)d_ws;
    half_t* Kp = (half_t*)((char*)d_ws + 1u * 1024u * 1024u);
    half_t* Vp = (half_t*)((char*)d_ws + 2u * 1024u * 1024u);
    half_t* Vt = (half_t*)((char*)d_ws + 3u * 1024u * 1024u);

    qkv_kernel<<<dim3(BB * NN), dim3(128), 0, stream>>>(q, Wq, Wk, Wv, Qh, Kp, Vp);
    vtrans_kernel<<<dim3(32 * 4), dim3(256), 0, stream>>>((const unsigned int*)Vp, Vt);
    fused_kernel<<<dim3(NN / NT, BB), dim3(512), 0, stream>>>(
        oss, st, Qh, (const unsigned int*)Kp, Vt,
        w1, b1, w2, b2, Wout, out);
}